// Round 6
// baseline (263.409 us; speedup 1.0000x reference)
//
#include <hip/hip_runtime.h>

// SLAYER 3-layer CUBA SNN — fused MFMA GEMM + leaky-IF scan.
// R6: (a) 32x32x16 bf16 MFMA (higher sustained rate, half the instructions),
// (b) K-loop restructured so glds16 of chunk k+1 is issued between the frag
// reads and the MFMA block of chunk k -> vmem latency hidden behind MFMA,
// (c) split_w + transpose merged into one prep kernel.
// Weights: W = hi + lo bf16 planes; spikes exact in bf16 (absmax 0.0 R3-R5).
// Layout m = b*128 + t: block holds full Z[t][o] history -> in-LDS scan.

typedef unsigned short ushort_t;
typedef unsigned int uint_t;
typedef __bf16 bf16x8 __attribute__((ext_vector_type(8)));
typedef float f32x16 __attribute__((ext_vector_type(16)));

#define O_TOT 1024

__device__ __forceinline__ void glds16(const ushort_t* g, ushort_t* l) {
  __builtin_amdgcn_global_load_lds(
      (const __attribute__((address_space(1))) uint_t*)g,
      (__attribute__((address_space(3))) uint_t*)l, 16, 0, 0);
}

__device__ __forceinline__ ushort_t f32_to_bf16_rne(float f) {
  uint_t u = __float_as_uint(f);
  u += 0x7FFFu + ((u >> 16) & 1u);
  return (ushort_t)(u >> 16);
}

// ---- prep: W1/W2 hi-lo split (blocks 0..12287) + spike transpose (rest) ----
__global__ __launch_bounds__(256) void prep(const float* __restrict__ W1,
                                            const float* __restrict__ W2,
                                            const float* __restrict__ spike,
                                            ushort_t* __restrict__ h1,
                                            ushort_t* __restrict__ l1,
                                            ushort_t* __restrict__ h2,
                                            ushort_t* __restrict__ l2,
                                            ushort_t* __restrict__ A1) {
  const int tid = threadIdx.x;
  if (blockIdx.x < 12288) {
    int idx = blockIdx.x * 256 + tid;
    const int N1 = 1024 * 2048;
    if (idx < N1) {
      float w = W1[idx];
      ushort_t h = f32_to_bf16_rne(w);
      h1[idx] = h;
      l1[idx] = f32_to_bf16_rne(w - __uint_as_float(((uint_t)h) << 16));
    } else {
      int k = idx - N1;
      float w = W2[k];
      ushort_t h = f32_to_bf16_rne(w);
      h2[k] = h;
      l2[k] = f32_to_bf16_rne(w - __uint_as_float(((uint_t)h) << 16));
    }
    return;
  }
  // spike [b][i][t] fp32 -> A1 [b*128+t][i] bf16
  __shared__ ushort_t lds[32 * 130];
  const int bid = blockIdx.x - 12288;  // 0..4095
  const int b = bid >> 6;
  const int i0 = (bid & 63) * 32;
#pragma unroll
  for (int it = 0; it < 4; ++it) {
    int p = it * 256 + tid;
    int i = p >> 5, tg = (p & 31) * 4;
    float4 v = *(const float4*)(spike + ((size_t)b * 2048 + i0 + i) * 128 + tg);
    lds[i * 130 + tg + 0] = (v.x != 0.0f) ? 0x3F80u : 0u;
    lds[i * 130 + tg + 1] = (v.y != 0.0f) ? 0x3F80u : 0u;
    lds[i * 130 + tg + 2] = (v.z != 0.0f) ? 0x3F80u : 0u;
    lds[i * 130 + tg + 3] = (v.w != 0.0f) ? 0x3F80u : 0u;
  }
  __syncthreads();
  uint_t* A1u = (uint_t*)A1;
#pragma unroll
  for (int it = 0; it < 8; ++it) {
    int p = it * 256 + tid;
    int t = p >> 4, iu = p & 15;
    uint_t u = (uint_t)lds[(2 * iu) * 130 + t] | ((uint_t)lds[(2 * iu + 1) * 130 + t] << 16);
    A1u[((size_t)(b * 128 + t) * 2048 + i0) / 2 + iu] = u;
  }
}

// ---- fused GEMM (128m x 64o, kc64, 32x32x16 MFMA, hi/lo bf16) + scan -------
// LDS slot swizzle: row = 8 x 16B-slots; slot(row,u) = row*8 + (u ^ (row&7)).
__global__ __launch_bounds__(256, 4)
void gemm_scan(const ushort_t* __restrict__ A, const ushort_t* __restrict__ Bhi,
               const ushort_t* __restrict__ Blo, ushort_t* __restrict__ S,
               int K) {
  __shared__ float smemf[128 * 65];   // 33,280 B
  ushort_t* As = (ushort_t*)smemf;    // 128 x 64 k (16 KB)
  ushort_t* Bh = As + 8192;           // 64 x 64 (8 KB)
  ushort_t* Bl = Bh + 4096;           // 8 KB
  float* Zt = smemf;                  // [128 t][65] epilogue overlay

  const int tid = threadIdx.x;
  const int wave = tid >> 6, lane = tid & 63;
  const int b = blockIdx.y;
  const int m0 = b * 128;
  const int o0 = blockIdx.x * 64;
  const int qm = wave >> 1, qn = wave & 1;
  const int r32 = lane & 31, h = lane >> 5;

  f32x16 acc[2];
#pragma unroll
  for (int i = 0; i < 2; ++i)
#pragma unroll
    for (int r = 0; r < 16; ++r) acc[i][r] = 0.0f;

  // staging source offsets. A: 1024 slots, 4 rounds/wave; B: 512/plane, 2.
  size_t gA[4];
  ushort_t* lA[4];
#pragma unroll
  for (int r = 0; r < 4; ++r) {
    int s = wave * 256 + r * 64 + lane;
    int row = s >> 3;
    int u = (s & 7) ^ (row & 7);
    gA[r] = (size_t)(m0 + row) * K + u * 8;
    lA[r] = As + (size_t)(wave * 256 + r * 64) * 8;
  }
  size_t gB[2];
  ushort_t *lBh[2], *lBl[2];
#pragma unroll
  for (int r = 0; r < 2; ++r) {
    int s = wave * 128 + r * 64 + lane;
    int row = s >> 3;
    int u = (s & 7) ^ (row & 7);
    gB[r] = (size_t)(o0 + row) * K + u * 8;
    lBh[r] = Bh + (size_t)(wave * 128 + r * 64) * 8;
    lBl[r] = Bl + (size_t)(wave * 128 + r * 64) * 8;
  }

  // frag LDS offsets: A row = qm*64+i*32+r32, B row = qn*32+r32; kstep s:
  // k-slot u0 = s*2+h, swizzled u = u0 ^ (row&7); offset = row*64 + u*8.
  int aoff[2][4], boff[4];
#pragma unroll
  for (int i = 0; i < 2; ++i) {
    int row = qm * 64 + i * 32 + r32;
#pragma unroll
    for (int s = 0; s < 4; ++s) aoff[i][s] = row * 64 + ((s * 2 + h) ^ (row & 7)) * 8;
  }
  {
    int row = qn * 32 + r32;
#pragma unroll
    for (int s = 0; s < 4; ++s) boff[s] = row * 64 + ((s * 2 + h) ^ (row & 7)) * 8;
  }

  // prologue: stage chunk 0
#pragma unroll
  for (int r = 0; r < 4; ++r) glds16(A + gA[r], lA[r]);
#pragma unroll
  for (int r = 0; r < 2; ++r) {
    glds16(Bhi + gB[r], lBh[r]);
    glds16(Blo + gB[r], lBl[r]);
  }
  __syncthreads();

  for (int kc = 0; kc < K; kc += 64) {
    // read all frags for this chunk into regs
    bf16x8 af[2][4], bh[4], bl[4];
#pragma unroll
    for (int i = 0; i < 2; ++i)
#pragma unroll
      for (int s = 0; s < 4; ++s) af[i][s] = *(const bf16x8*)(As + aoff[i][s]);
#pragma unroll
    for (int s = 0; s < 4; ++s) {
      bh[s] = *(const bf16x8*)(Bh + boff[s]);
      bl[s] = *(const bf16x8*)(Bl + boff[s]);
    }
    __syncthreads();  // all waves done reading LDS (no vmem outstanding)

    // prefetch next chunk into LDS — overlaps with MFMA below
    if (kc + 64 < K) {
      int kn = kc + 64;
#pragma unroll
      for (int r = 0; r < 4; ++r) glds16(A + gA[r] + kn, lA[r]);
#pragma unroll
      for (int r = 0; r < 2; ++r) {
        glds16(Bhi + gB[r] + kn, lBh[r]);
        glds16(Blo + gB[r] + kn, lBl[r]);
      }
    }

#pragma unroll
    for (int s = 0; s < 4; ++s)
#pragma unroll
      for (int i = 0; i < 2; ++i) {
        acc[i] = __builtin_amdgcn_mfma_f32_32x32x16_bf16(af[i][s], bh[s], acc[i], 0, 0, 0);
        acc[i] = __builtin_amdgcn_mfma_f32_32x32x16_bf16(af[i][s], bl[s], acc[i], 0, 0, 0);
      }
    __syncthreads();  // drains prefetch vmcnt (mostly landed during MFMA)
  }

  // acc -> LDS Z-tile: C/D layout col=r32, row=(reg&3)+8*(reg>>2)+4*h
#pragma unroll
  for (int i = 0; i < 2; ++i)
#pragma unroll
    for (int reg = 0; reg < 16; ++reg) {
      int t = qm * 64 + i * 32 + (reg & 3) + 8 * (reg >> 2) + 4 * h;
      Zt[t * 65 + qn * 32 + r32] = acc[i][reg];
    }
  __syncthreads();

  // fused leaky-IF scan: thread tid<64 owns o-column (o0+tid)
  if (tid < 64) {
#pragma clang fp contract(off)
    float cur = 0.0f, vol = 0.0f;
    const int o = o0 + tid;
    for (int t = 0; t < 128; ++t) {
      float z = Zt[t * 65 + tid];
      cur = cur * 0.7f;
      cur = cur + z;
      vol = vol * 0.2f;
      vol = vol + cur;
      float v = vol - 1.0f;
      float s = (v >= 0.0f) ? 1.0f : 0.0f;
      vol = vol * (1.0f - s);
      S[(size_t)(m0 + t) * O_TOT + o] = (v >= 0.0f) ? 0x3F80u : 0u;
    }
  }
}

// ---------- layer 3 fused: per-b dense (O=2, fp32) + scan + output ----------
__global__ __launch_bounds__(256) void gemm3_scan(const ushort_t* __restrict__ X,
                                                  const float* __restrict__ W3,
                                                  float* __restrict__ out) {
  __shared__ float w3s[2048];
  __shared__ float z3[256];  // [t*2 + o]
  __shared__ float sp[256];  // [o*128 + t]
  const int tid = threadIdx.x;
  const int b = blockIdx.x;
  for (int i = tid; i < 2048; i += 256) w3s[i] = W3[i];
  __syncthreads();
  const int wave = tid >> 6, lane = tid & 63;
  for (int tt = 0; tt < 32; ++tt) {
    int t = wave * 32 + tt;
    const uint_t* row = (const uint_t*)(X + (size_t)(b * 128 + t) * 1024) + lane * 8;
    float s0 = 0.0f, s1 = 0.0f;
#pragma unroll
    for (int jw = 0; jw < 8; ++jw) {
      uint_t u = row[jw];
      float x0 = __uint_as_float(u << 16);
      float x1 = __uint_as_float(u & 0xFFFF0000u);
      int i0 = lane * 16 + jw * 2;
      s0 = fmaf(x0, w3s[i0], s0);
      s1 = fmaf(x0, w3s[1024 + i0], s1);
      s0 = fmaf(x1, w3s[i0 + 1], s0);
      s1 = fmaf(x1, w3s[1024 + i0 + 1], s1);
    }
#pragma unroll
    for (int off = 32; off > 0; off >>= 1) {
      s0 += __shfl_down(s0, off);
      s1 += __shfl_down(s1, off);
    }
    if (lane == 0) {
      z3[t * 2] = s0;
      z3[t * 2 + 1] = s1;
    }
  }
  __syncthreads();
  if (tid < 2) {
#pragma clang fp contract(off)
    float cur = 0.0f, vol = 0.0f;
    for (int t = 0; t < 128; ++t) {
      float z = z3[t * 2 + tid];
      cur = cur * 0.7f;
      cur = cur + z;
      vol = vol * 0.2f;
      vol = vol + cur;
      float v = vol - 1.0f;
      float s = (v >= 0.0f) ? 1.0f : 0.0f;
      vol = vol * (1.0f - s);
      sp[tid * 128 + t] = s;
    }
  }
  __syncthreads();
  out[b * 256 + tid] = sp[tid];
}

extern "C" void kernel_launch(void* const* d_in, const int* in_sizes, int n_in,
                              void* d_out, int out_size, void* d_ws, size_t ws_size,
                              hipStream_t stream) {
  const float* spike = (const float*)d_in[0];  // [64, 2048, 128]
  const float* W1 = (const float*)d_in[1];     // [1024, 2048]
  const float* W2 = (const float*)d_in[2];     // [1024, 1024]
  const float* W3 = (const float*)d_in[3];     // [2, 1024]
  float* out = (float*)d_out;                  // [64, 2, 128]

  char* ws = (char*)d_ws;
  ushort_t* A1 = (ushort_t*)ws;                                 // 32 MB
  ushort_t* S2 = (ushort_t*)(ws + (size_t)32 * 1024 * 1024);    // 16 MB
  ushort_t* S3 = (ushort_t*)(ws + (size_t)48 * 1024 * 1024);    // 16 MB
  ushort_t* W1hi = (ushort_t*)(ws + (size_t)64 * 1024 * 1024);  // 4 MB
  ushort_t* W1lo = (ushort_t*)(ws + (size_t)68 * 1024 * 1024);  // 4 MB
  ushort_t* W2hi = (ushort_t*)(ws + (size_t)72 * 1024 * 1024);  // 2 MB
  ushort_t* W2lo = (ushort_t*)(ws + (size_t)74 * 1024 * 1024);  // 2 MB

  prep<<<16384, 256, 0, stream>>>(W1, W2, spike, W1hi, W1lo, W2hi, W2lo, A1);
  // L1: M=8192 (b*128+t), K=2048, O=1024
  gemm_scan<<<dim3(16, 64), 256, 0, stream>>>(A1, W1hi, W1lo, S2, 2048);
  // L2: K=1024
  gemm_scan<<<dim3(16, 64), 256, 0, stream>>>(S2, W2hi, W2lo, S3, 1024);
  // L3 + final scan + output
  gemm3_scan<<<64, 256, 0, stream>>>(S3, W3, out);
}

// Round 7
// 237.656 us; speedup vs baseline: 1.1084x; 1.1084x over previous
//
#include <hip/hip_runtime.h>

// SLAYER 3-layer CUBA SNN — fused MFMA GEMM + leaky-IF scan.
// R7: gemm_scan reverted to the proven R5 core (16x16x32 MFMA, kc=64, XOR
// slot swizzle, stage->barrier->compute->barrier). R6's 32x32 MFMA + prefetch
// restructure regressed (conflicts 2^23, MfmaUtil -9) — reverted.
// New: prep uses a 128-wide i-tile transpose -> A1 stores are 512B/wave uint2
// runs (4x better coalescing than the 64B segments of the 32-wide tile).
// Weights: W = hi + lo bf16 planes; spikes exact in bf16 (absmax 0.0 R3-R5).
// Layout m = b*128 + t: block holds full Z[t][o] history -> in-LDS scan.

typedef unsigned short ushort_t;
typedef unsigned int uint_t;
typedef __bf16 bf16x8 __attribute__((ext_vector_type(8)));
typedef float f32x4 __attribute__((ext_vector_type(4)));

#define O_TOT 1024

__device__ __forceinline__ void glds16(const ushort_t* g, ushort_t* l) {
  __builtin_amdgcn_global_load_lds(
      (const __attribute__((address_space(1))) uint_t*)g,
      (__attribute__((address_space(3))) uint_t*)l, 16, 0, 0);
}

__device__ __forceinline__ ushort_t f32_to_bf16_rne(float f) {
  uint_t u = __float_as_uint(f);
  u += 0x7FFFu + ((u >> 16) & 1u);
  return (ushort_t)(u >> 16);
}

// ---- prep: W1/W2 hi-lo split (blocks 0..12287) + spike transpose (rest) ----
// transpose part: block = (b, i-tile of 128); spike [b][i][t] f32 -> A1
// [b*128+t][i] bf16 via LDS; stores are uint2 (512 B per wave instruction).
__global__ __launch_bounds__(256) void prep(const float* __restrict__ W1,
                                            const float* __restrict__ W2,
                                            const float* __restrict__ spike,
                                            ushort_t* __restrict__ h1,
                                            ushort_t* __restrict__ l1,
                                            ushort_t* __restrict__ h2,
                                            ushort_t* __restrict__ l2,
                                            ushort_t* __restrict__ A1) {
  const int tid = threadIdx.x;
  if (blockIdx.x < 12288) {
    int idx = blockIdx.x * 256 + tid;
    const int N1 = 1024 * 2048;
    if (idx < N1) {
      float w = W1[idx];
      ushort_t h = f32_to_bf16_rne(w);
      h1[idx] = h;
      l1[idx] = f32_to_bf16_rne(w - __uint_as_float(((uint_t)h) << 16));
    } else {
      int k = idx - N1;
      float w = W2[k];
      ushort_t h = f32_to_bf16_rne(w);
      h2[k] = h;
      l2[k] = f32_to_bf16_rne(w - __uint_as_float(((uint_t)h) << 16));
    }
    return;
  }
  __shared__ ushort_t lds[128 * 130];  // [i][t] padded, 33,280 B
  const int bid = blockIdx.x - 12288;  // 0..1023
  const int b = bid >> 4;
  const int i0 = (bid & 15) * 128;
#pragma unroll
  for (int it = 0; it < 16; ++it) {
    int p = it * 256 + tid;
    int i = p >> 5, tg = (p & 31) * 4;
    float4 v = *(const float4*)(spike + ((size_t)b * 2048 + i0 + i) * 128 + tg);
    lds[i * 130 + tg + 0] = (v.x != 0.0f) ? 0x3F80u : 0u;
    lds[i * 130 + tg + 1] = (v.y != 0.0f) ? 0x3F80u : 0u;
    lds[i * 130 + tg + 2] = (v.z != 0.0f) ? 0x3F80u : 0u;
    lds[i * 130 + tg + 3] = (v.w != 0.0f) ? 0x3F80u : 0u;
  }
  __syncthreads();
#pragma unroll
  for (int it = 0; it < 16; ++it) {
    int p = it * 256 + tid;
    int t = p >> 5, j = p & 31;  // j: uint2 index (4 ushorts)
    uint_t u0 = (uint_t)lds[(4 * j + 0) * 130 + t] | ((uint_t)lds[(4 * j + 1) * 130 + t] << 16);
    uint_t u1 = (uint_t)lds[(4 * j + 2) * 130 + t] | ((uint_t)lds[(4 * j + 3) * 130 + t] << 16);
    uint2* dst = (uint2*)(A1 + (size_t)(b * 128 + t) * 2048 + i0);
    dst[j] = make_uint2(u0, u1);
  }
}

// ------- fused GEMM (128m x 64o tile, kc64, hi/lo bf16) + scan --------------
// LDS slot swizzle: tile row has 8 16B-slots (64 bf16); slot(row,u) =
// row*8 + (u ^ (row&7)) -> frag ds_read_b128 covers all 32 banks per 8 lanes.
__global__ __launch_bounds__(256, 4)
void gemm_scan(const ushort_t* __restrict__ A, const ushort_t* __restrict__ Bhi,
               const ushort_t* __restrict__ Blo, ushort_t* __restrict__ S,
               int K) {
  __shared__ float smemf[128 * 65];   // 33,280 B
  ushort_t* As = (ushort_t*)smemf;    // 128 x 64 k (16 KB)
  ushort_t* Bh = As + 8192;           // 64 x 64 (8 KB)
  ushort_t* Bl = Bh + 4096;           // 8 KB
  float* Zt = smemf;                  // [128 t][65] epilogue overlay

  const int tid = threadIdx.x;
  const int wave = tid >> 6, lane = tid & 63;
  const int b = blockIdx.y;
  const int m0 = b * 128;
  const int o0 = blockIdx.x * 64;
  const int qm = wave >> 1, qn = wave & 1;
  const int fr = lane & 15, q = lane >> 4;

  f32x4 acc[4][2];
#pragma unroll
  for (int i = 0; i < 4; ++i)
#pragma unroll
    for (int j = 0; j < 2; ++j) acc[i][j] = (f32x4){0.f, 0.f, 0.f, 0.f};

  // staging source offsets (ushort elems). A: 1024 slots, 4 rounds/wave.
  size_t gA[4];
  ushort_t* lA[4];
#pragma unroll
  for (int r = 0; r < 4; ++r) {
    int s = wave * 256 + r * 64 + lane;
    int row = s >> 3;
    int u = (s & 7) ^ (row & 7);
    gA[r] = (size_t)(m0 + row) * K + u * 8;
    lA[r] = As + (size_t)(wave * 256 + r * 64) * 8;
  }
  // B: 512 slots/plane, 2 rounds/wave.
  size_t gB[2];
  ushort_t *lBh[2], *lBl[2];
#pragma unroll
  for (int r = 0; r < 2; ++r) {
    int s = wave * 128 + r * 64 + lane;
    int row = s >> 3;
    int u = (s & 7) ^ (row & 7);
    gB[r] = (size_t)(o0 + row) * K + u * 8;
    lBh[r] = Bh + (size_t)(wave * 128 + r * 64) * 8;
    lBl[r] = Bl + (size_t)(wave * 128 + r * 64) * 8;
  }

  // frag LDS offsets (swizzled), per kk half
  int aoff[4][2], boff[2][2];
#pragma unroll
  for (int i = 0; i < 4; ++i)
#pragma unroll
    for (int kk = 0; kk < 2; ++kk) {
      int row = qm * 64 + i * 16 + fr;
      int u = (kk * 4 + q) ^ (row & 7);
      aoff[i][kk] = row * 64 + u * 8;
    }
#pragma unroll
  for (int j = 0; j < 2; ++j)
#pragma unroll
    for (int kk = 0; kk < 2; ++kk) {
      int row = qn * 32 + j * 16 + fr;
      int u = (kk * 4 + q) ^ (row & 7);
      boff[j][kk] = row * 64 + u * 8;
    }

  for (int kc = 0; kc < K; kc += 64) {
#pragma unroll
    for (int r = 0; r < 4; ++r) glds16(A + gA[r] + kc, lA[r]);
#pragma unroll
    for (int r = 0; r < 2; ++r) {
      glds16(Bhi + gB[r] + kc, lBh[r]);
      glds16(Blo + gB[r] + kc, lBl[r]);
    }
    __syncthreads();

#pragma unroll
    for (int kk = 0; kk < 2; ++kk) {
      bf16x8 af[4], bh[2], bl[2];
#pragma unroll
      for (int i = 0; i < 4; ++i) af[i] = *(const bf16x8*)(As + aoff[i][kk]);
#pragma unroll
      for (int j = 0; j < 2; ++j) {
        bh[j] = *(const bf16x8*)(Bh + boff[j][kk]);
        bl[j] = *(const bf16x8*)(Bl + boff[j][kk]);
      }
#pragma unroll
      for (int i = 0; i < 4; ++i)
#pragma unroll
        for (int j = 0; j < 2; ++j) {
          acc[i][j] = __builtin_amdgcn_mfma_f32_16x16x32_bf16(af[i], bh[j], acc[i][j], 0, 0, 0);
          acc[i][j] = __builtin_amdgcn_mfma_f32_16x16x32_bf16(af[i], bl[j], acc[i][j], 0, 0, 0);
        }
    }
    __syncthreads();
  }

  // acc -> LDS Z-tile: t = qm*64+i*16+q*4+rr, o-local = qn*32+j*16+fr
#pragma unroll
  for (int i = 0; i < 4; ++i)
#pragma unroll
    for (int j = 0; j < 2; ++j)
#pragma unroll
      for (int rr = 0; rr < 4; ++rr)
        Zt[(qm * 64 + i * 16 + q * 4 + rr) * 65 + qn * 32 + j * 16 + fr] = acc[i][j][rr];
  __syncthreads();

  // fused leaky-IF scan: thread tid<64 owns o-column (o0+tid)
  if (tid < 64) {
#pragma clang fp contract(off)
    float cur = 0.0f, vol = 0.0f;
    const int o = o0 + tid;
    for (int t = 0; t < 128; ++t) {
      float z = Zt[t * 65 + tid];
      cur = cur * 0.7f;
      cur = cur + z;
      vol = vol * 0.2f;
      vol = vol + cur;
      float v = vol - 1.0f;
      float s = (v >= 0.0f) ? 1.0f : 0.0f;
      vol = vol * (1.0f - s);
      S[(size_t)(m0 + t) * O_TOT + o] = (v >= 0.0f) ? 0x3F80u : 0u;
    }
  }
}

// ---------- layer 3 fused: per-b dense (O=2, fp32) + scan + output ----------
__global__ __launch_bounds__(256) void gemm3_scan(const ushort_t* __restrict__ X,
                                                  const float* __restrict__ W3,
                                                  float* __restrict__ out) {
  __shared__ float w3s[2048];
  __shared__ float z3[256];  // [t*2 + o]
  __shared__ float sp[256];  // [o*128 + t]
  const int tid = threadIdx.x;
  const int b = blockIdx.x;
  for (int i = tid; i < 2048; i += 256) w3s[i] = W3[i];
  __syncthreads();
  const int wave = tid >> 6, lane = tid & 63;
  for (int tt = 0; tt < 32; ++tt) {
    int t = wave * 32 + tt;
    const uint_t* row = (const uint_t*)(X + (size_t)(b * 128 + t) * 1024) + lane * 8;
    float s0 = 0.0f, s1 = 0.0f;
#pragma unroll
    for (int jw = 0; jw < 8; ++jw) {
      uint_t u = row[jw];
      float x0 = __uint_as_float(u << 16);
      float x1 = __uint_as_float(u & 0xFFFF0000u);
      int i0 = lane * 16 + jw * 2;
      s0 = fmaf(x0, w3s[i0], s0);
      s1 = fmaf(x0, w3s[1024 + i0], s1);
      s0 = fmaf(x1, w3s[i0 + 1], s0);
      s1 = fmaf(x1, w3s[1024 + i0 + 1], s1);
    }
#pragma unroll
    for (int off = 32; off > 0; off >>= 1) {
      s0 += __shfl_down(s0, off);
      s1 += __shfl_down(s1, off);
    }
    if (lane == 0) {
      z3[t * 2] = s0;
      z3[t * 2 + 1] = s1;
    }
  }
  __syncthreads();
  if (tid < 2) {
#pragma clang fp contract(off)
    float cur = 0.0f, vol = 0.0f;
    for (int t = 0; t < 128; ++t) {
      float z = z3[t * 2 + tid];
      cur = cur * 0.7f;
      cur = cur + z;
      vol = vol * 0.2f;
      vol = vol + cur;
      float v = vol - 1.0f;
      float s = (v >= 0.0f) ? 1.0f : 0.0f;
      vol = vol * (1.0f - s);
      sp[tid * 128 + t] = s;
    }
  }
  __syncthreads();
  out[b * 256 + tid] = sp[tid];
}

extern "C" void kernel_launch(void* const* d_in, const int* in_sizes, int n_in,
                              void* d_out, int out_size, void* d_ws, size_t ws_size,
                              hipStream_t stream) {
  const float* spike = (const float*)d_in[0];  // [64, 2048, 128]
  const float* W1 = (const float*)d_in[1];     // [1024, 2048]
  const float* W2 = (const float*)d_in[2];     // [1024, 1024]
  const float* W3 = (const float*)d_in[3];     // [2, 1024]
  float* out = (float*)d_out;                  // [64, 2, 128]

  char* ws = (char*)d_ws;
  ushort_t* A1 = (ushort_t*)ws;                                 // 32 MB
  ushort_t* S2 = (ushort_t*)(ws + (size_t)32 * 1024 * 1024);    // 16 MB
  ushort_t* S3 = (ushort_t*)(ws + (size_t)48 * 1024 * 1024);    // 16 MB
  ushort_t* W1hi = (ushort_t*)(ws + (size_t)64 * 1024 * 1024);  // 4 MB
  ushort_t* W1lo = (ushort_t*)(ws + (size_t)68 * 1024 * 1024);  // 4 MB
  ushort_t* W2hi = (ushort_t*)(ws + (size_t)72 * 1024 * 1024);  // 2 MB
  ushort_t* W2lo = (ushort_t*)(ws + (size_t)74 * 1024 * 1024);  // 2 MB

  // blocks 0..12287: W split; 12288..13311: spike transpose (64 b x 16 i-tiles)
  prep<<<13312, 256, 0, stream>>>(W1, W2, spike, W1hi, W1lo, W2hi, W2lo, A1);
  // L1: M=8192 (b*128+t), K=2048, O=1024
  gemm_scan<<<dim3(16, 64), 256, 0, stream>>>(A1, W1hi, W1lo, S2, 2048);
  // L2: K=1024
  gemm_scan<<<dim3(16, 64), 256, 0, stream>>>(S2, W2hi, W2lo, S3, 1024);
  // L3 + final scan + output
  gemm3_scan<<<64, 256, 0, stream>>>(S3, W3, out);
}